// Round 1
// baseline (1434.171 us; speedup 1.0000x reference)
//
#include <hip/hip_runtime.h>

#define THREADS 256

__global__ __launch_bounds__(THREADS)
void dueling_fwd(const float* __restrict__ state,   // (B,78)
                 const float* __restrict__ emb,     // (450,8)
                 const float* __restrict__ wd1, const float* __restrict__ bd1,
                 const float* __restrict__ wd2, const float* __restrict__ bd2,
                 const float* __restrict__ wt1, const float* __restrict__ bt1,
                 const float* __restrict__ wt2, const float* __restrict__ bt2,
                 const float* __restrict__ wv1, const float* __restrict__ bv1,
                 const float* __restrict__ wv2, const float* __restrict__ bv2,
                 const float* __restrict__ wv3, const float* __restrict__ bv3,
                 const float* __restrict__ ws1, const float* __restrict__ bs1,
                 const float* __restrict__ ws2, const float* __restrict__ bs2,
                 const float* __restrict__ wp1, const float* __restrict__ bp1,
                 const float* __restrict__ wp2, const float* __restrict__ bp2,
                 const float* __restrict__ wp3, const float* __restrict__ bp3,
                 float* __restrict__ out, int nrows)
{
    const int row = blockIdx.x * THREADS + threadIdx.x;
    if (row >= nrows) return;
    const float* __restrict__ s = state + (long long)row * 78;

    //===================== defender head: 5 x (4->32 relu ->32 relu), mean pool =====================
    float def_pooled[32];
#pragma unroll
    for (int n = 0; n < 32; ++n) def_pooled[n] = 0.0f;

#pragma unroll 1
    for (int p = 0; p < 5; ++p) {
        const float f0 = s[23 + 2 * p];   // def_pos x
        const float f1 = s[24 + 2 * p];   // def_pos y
        const float f2 = s[43 + 2 * p];   // def_vel x
        const float f3 = s[44 + 2 * p];   // def_vel y
        float h1[32];
#pragma unroll
        for (int n = 0; n < 32; ++n) {
            float a = bd1[n];
            a = fmaf(f0, wd1[0 * 32 + n], a);
            a = fmaf(f1, wd1[1 * 32 + n], a);
            a = fmaf(f2, wd1[2 * 32 + n], a);
            a = fmaf(f3, wd1[3 * 32 + n], a);
            h1[n] = fmaxf(a, 0.0f);
        }
        float a2[32];
#pragma unroll
        for (int n = 0; n < 32; ++n) a2[n] = bd2[n];
#pragma unroll
        for (int k = 0; k < 32; ++k) {
            const float hk = h1[k];
#pragma unroll
            for (int n = 0; n < 32; ++n) a2[n] = fmaf(hk, wd2[k * 32 + n], a2[n]);
        }
#pragma unroll
        for (int n = 0; n < 32; ++n) def_pooled[n] += fmaxf(a2[n], 0.0f);
    }

    //===================== base (53) = [context(11), bh_vel(2), bh_embed(8), def_pooled(32)] =====================
    float base[53];
#pragma unroll
    for (int i = 0; i < 11; ++i) base[i] = s[i];
    base[11] = s[41];
    base[12] = s[42];
    {
        int pid0 = (int)s[73];
        pid0 = pid0 < 0 ? 0 : (pid0 > 449 ? 449 : pid0);
        const float4 e0 = *(const float4*)(emb + pid0 * 8);
        const float4 e1 = *(const float4*)(emb + pid0 * 8 + 4);
        base[13] = e0.x; base[14] = e0.y; base[15] = e0.z; base[16] = e0.w;
        base[17] = e1.x; base[18] = e1.y; base[19] = e1.z; base[20] = e1.w;
    }
#pragma unroll
    for (int n = 0; n < 32; ++n) base[21 + n] = def_pooled[n] * 0.2f;  // mean over 5

    //===================== value head: 53->64 relu ->32 relu ->1 =====================
    float value;
    {
        float h64[64];
#pragma unroll
        for (int n = 0; n < 64; ++n) h64[n] = bv1[n];
#pragma unroll
        for (int k = 0; k < 53; ++k) {
            const float xk = base[k];
#pragma unroll
            for (int n = 0; n < 64; ++n) h64[n] = fmaf(xk, wv1[k * 64 + n], h64[n]);
        }
#pragma unroll
        for (int n = 0; n < 64; ++n) h64[n] = fmaxf(h64[n], 0.0f);

        float h32[32];
#pragma unroll
        for (int n = 0; n < 32; ++n) h32[n] = bv2[n];
#pragma unroll
        for (int k = 0; k < 64; ++k) {
            const float xk = h64[k];
#pragma unroll
            for (int n = 0; n < 32; ++n) h32[n] = fmaf(xk, wv2[k * 32 + n], h32[n]);
        }
        value = bv3[0];
#pragma unroll
        for (int k = 0; k < 32; ++k) value = fmaf(fmaxf(h32[k], 0.0f), wv3[k], value);
    }

    //===================== shoot head: 53->32 relu ->1 =====================
    float a_shoot;
    {
        float t[32];
#pragma unroll
        for (int n = 0; n < 32; ++n) t[n] = bs1[n];
#pragma unroll
        for (int k = 0; k < 53; ++k) {
            const float xk = base[k];
#pragma unroll
            for (int n = 0; n < 32; ++n) t[n] = fmaf(xk, ws1[k * 32 + n], t[n]);
        }
        a_shoot = bs2[0];
#pragma unroll
        for (int k = 0; k < 32; ++k) a_shoot = fmaf(fmaxf(t[k], 0.0f), ws2[k], a_shoot);
    }

    //===================== pass head, shared part: base @ wp1[32:85] + bp1 =====================
    float pb[64];
#pragma unroll
    for (int n = 0; n < 64; ++n) pb[n] = bp1[n];
#pragma unroll
    for (int k = 0; k < 53; ++k) {
        const float xk = base[k];
#pragma unroll
        for (int n = 0; n < 64; ++n) pb[n] = fmaf(xk, wp1[(32 + k) * 64 + n], pb[n]);
    }

    //===================== teammates: phi (18->32 relu ->32 relu), pass (85->64 relu ->16 relu ->1) =====================
    float ap0 = 0.f, ap1 = 0.f, ap2 = 0.f, ap3 = 0.f;
#pragma unroll 1
    for (int j = 0; j < 4; ++j) {
        float tf[18];
        tf[0] = s[33 + 2 * j];   // tm_pos x
        tf[1] = s[34 + 2 * j];   // tm_pos y
        tf[2] = s[53 + 2 * j];   // tm_vel x
        tf[3] = s[54 + 2 * j];   // tm_vel y
        tf[4] = s[11 + j];       // tm_open
        tf[5] = s[15 + j];       // tm_fg
        tf[6] = s[19 + j];       // tm_dist
        tf[7] = s[61 + j];       // tm_lane_min
        tf[8] = s[65 + j];       // tm_corridor
        tf[9] = s[69 + j];       // tm_pass_dist
        {
            int pid = (int)s[74 + j];
            pid = pid < 0 ? 0 : (pid > 449 ? 449 : pid);
            const float4 e0 = *(const float4*)(emb + pid * 8);
            const float4 e1 = *(const float4*)(emb + pid * 8 + 4);
            tf[10] = e0.x; tf[11] = e0.y; tf[12] = e0.z; tf[13] = e0.w;
            tf[14] = e1.x; tf[15] = e1.y; tf[16] = e1.z; tf[17] = e1.w;
        }

        float t1[32];
#pragma unroll
        for (int n = 0; n < 32; ++n) t1[n] = bt1[n];
#pragma unroll
        for (int k = 0; k < 18; ++k) {
            const float xk = tf[k];
#pragma unroll
            for (int n = 0; n < 32; ++n) t1[n] = fmaf(xk, wt1[k * 32 + n], t1[n]);
        }
#pragma unroll
        for (int n = 0; n < 32; ++n) t1[n] = fmaxf(t1[n], 0.0f);

        float t2[32];
#pragma unroll
        for (int n = 0; n < 32; ++n) t2[n] = bt2[n];
#pragma unroll
        for (int k = 0; k < 32; ++k) {
            const float xk = t1[k];
#pragma unroll
            for (int n = 0; n < 32; ++n) t2[n] = fmaf(xk, wt2[k * 32 + n], t2[n]);
        }
#pragma unroll
        for (int n = 0; n < 32; ++n) t2[n] = fmaxf(t2[n], 0.0f);  // tm_phi

        float ph[64];
#pragma unroll
        for (int n = 0; n < 64; ++n) ph[n] = pb[n];
#pragma unroll
        for (int k = 0; k < 32; ++k) {
            const float xk = t2[k];
#pragma unroll
            for (int n = 0; n < 64; ++n) ph[n] = fmaf(xk, wp1[k * 64 + n], ph[n]);
        }
#pragma unroll
        for (int n = 0; n < 64; ++n) ph[n] = fmaxf(ph[n], 0.0f);

        float p2[16];
#pragma unroll
        for (int n = 0; n < 16; ++n) p2[n] = bp2[n];
#pragma unroll
        for (int k = 0; k < 64; ++k) {
            const float xk = ph[k];
#pragma unroll
            for (int n = 0; n < 16; ++n) p2[n] = fmaf(xk, wp2[k * 16 + n], p2[n]);
        }
        float a = bp3[0];
#pragma unroll
        for (int k = 0; k < 16; ++k) a = fmaf(fmaxf(p2[k], 0.0f), wp3[k], a);

        if (j == 0) ap0 = a;
        else if (j == 1) ap1 = a;
        else if (j == 2) ap2 = a;
        else ap3 = a;
    }

    //===================== combine & store =====================
    const float am = 0.25f * (ap0 + ap1 + ap2 + ap3);
    const float q0 = value + a_shoot;
    float* __restrict__ o = out + (long long)row * 5;
    o[0] = q0;
    o[1] = value + ap0 - am;
    o[2] = value + ap1 - am;
    o[3] = value + ap2 - am;
    o[4] = value + ap3 - am;
}

extern "C" void kernel_launch(void* const* d_in, const int* in_sizes, int n_in,
                              void* d_out, int out_size, void* d_ws, size_t ws_size,
                              hipStream_t stream)
{
    const float* state = (const float*)d_in[0];
    const float* emb   = (const float*)d_in[1];
    const float* wd1 = (const float*)d_in[2];  const float* bd1 = (const float*)d_in[3];
    const float* wd2 = (const float*)d_in[4];  const float* bd2 = (const float*)d_in[5];
    const float* wt1 = (const float*)d_in[6];  const float* bt1 = (const float*)d_in[7];
    const float* wt2 = (const float*)d_in[8];  const float* bt2 = (const float*)d_in[9];
    const float* wv1 = (const float*)d_in[10]; const float* bv1 = (const float*)d_in[11];
    const float* wv2 = (const float*)d_in[12]; const float* bv2 = (const float*)d_in[13];
    const float* wv3 = (const float*)d_in[14]; const float* bv3 = (const float*)d_in[15];
    const float* ws1 = (const float*)d_in[16]; const float* bs1 = (const float*)d_in[17];
    const float* ws2 = (const float*)d_in[18]; const float* bs2 = (const float*)d_in[19];
    const float* wp1 = (const float*)d_in[20]; const float* bp1 = (const float*)d_in[21];
    const float* wp2 = (const float*)d_in[22]; const float* bp2 = (const float*)d_in[23];
    const float* wp3 = (const float*)d_in[24]; const float* bp3 = (const float*)d_in[25];

    const int nrows = in_sizes[0] / 78;
    const int blocks = (nrows + THREADS - 1) / THREADS;
    dueling_fwd<<<blocks, THREADS, 0, stream>>>(
        state, emb,
        wd1, bd1, wd2, bd2, wt1, bt1, wt2, bt2,
        wv1, bv1, wv2, bv2, wv3, bv3, ws1, bs1, ws2, bs2,
        wp1, bp1, wp2, bp2, wp3, bp3,
        (float*)d_out, nrows);
}

// Round 2
// 660.650 us; speedup vs baseline: 2.1708x; 2.1708x over previous
//
#include <hip/hip_runtime.h>

#define THREADS 256

__global__ __launch_bounds__(THREADS, 3)
void dueling_fwd(const float* __restrict__ state,   // (B,78)
                 const float* __restrict__ emb,     // (450,8)
                 const float* __restrict__ wd1, const float* __restrict__ bd1,
                 const float* __restrict__ wd2, const float* __restrict__ bd2,
                 const float* __restrict__ wt1, const float* __restrict__ bt1,
                 const float* __restrict__ wt2, const float* __restrict__ bt2,
                 const float* __restrict__ wv1, const float* __restrict__ bv1,
                 const float* __restrict__ wv2, const float* __restrict__ bv2,
                 const float* __restrict__ wv3, const float* __restrict__ bv3,
                 const float* __restrict__ ws1, const float* __restrict__ bs1,
                 const float* __restrict__ ws2, const float* __restrict__ bs2,
                 const float* __restrict__ wp1, const float* __restrict__ bp1,
                 const float* __restrict__ wp2, const float* __restrict__ bp2,
                 const float* __restrict__ wp3, const float* __restrict__ bp3,
                 float* __restrict__ out, int nrows)
{
    const int row = blockIdx.x * THREADS + threadIdx.x;
    if (row >= nrows) return;
    const float* __restrict__ s = state + (long long)row * 78;

    //===================== defender head: 5 x (4->32 relu ->32 relu), mean pool =====================
    float def_pooled[32];
#pragma unroll
    for (int n = 0; n < 32; ++n) def_pooled[n] = 0.0f;

#pragma unroll 1
    for (int p = 0; p < 5; ++p) {
        const float f0 = s[23 + 2 * p];   // def_pos x
        const float f1 = s[24 + 2 * p];   // def_pos y
        const float f2 = s[43 + 2 * p];   // def_vel x
        const float f3 = s[44 + 2 * p];   // def_vel y
        float h1[32];
#pragma unroll
        for (int n = 0; n < 32; ++n) {
            float a = bd1[n];
            a = fmaf(f0, wd1[0 * 32 + n], a);
            a = fmaf(f1, wd1[1 * 32 + n], a);
            a = fmaf(f2, wd1[2 * 32 + n], a);
            a = fmaf(f3, wd1[3 * 32 + n], a);
            h1[n] = fmaxf(a, 0.0f);
        }
        float a2[32];
#pragma unroll
        for (int n = 0; n < 32; ++n) a2[n] = bd2[n];
#pragma unroll
        for (int k = 0; k < 32; ++k) {
            const float hk = h1[k];
#pragma unroll
            for (int n = 0; n < 32; ++n) a2[n] = fmaf(hk, wd2[k * 32 + n], a2[n]);
        }
#pragma unroll
        for (int n = 0; n < 32; ++n) def_pooled[n] += fmaxf(a2[n], 0.0f);
    }

    //===================== base (53) = [context(11), bh_vel(2), bh_embed(8), def_pooled(32)] =====================
    float base[53];
#pragma unroll
    for (int i = 0; i < 11; ++i) base[i] = s[i];
    base[11] = s[41];
    base[12] = s[42];
    {
        int pid0 = (int)s[73];
        pid0 = pid0 < 0 ? 0 : (pid0 > 449 ? 449 : pid0);
        const float4 e0 = *(const float4*)(emb + pid0 * 8);
        const float4 e1 = *(const float4*)(emb + pid0 * 8 + 4);
        base[13] = e0.x; base[14] = e0.y; base[15] = e0.z; base[16] = e0.w;
        base[17] = e1.x; base[18] = e1.y; base[19] = e1.z; base[20] = e1.w;
    }
#pragma unroll
    for (int n = 0; n < 32; ++n) base[21 + n] = def_pooled[n] * 0.2f;  // mean over 5

    //===================== shoot head: 53->32 relu ->1 (smallest temps first) =====================
    float a_shoot;
    {
        float t[32];
#pragma unroll
        for (int n = 0; n < 32; ++n) t[n] = bs1[n];
#pragma unroll
        for (int k = 0; k < 53; ++k) {
            const float xk = base[k];
#pragma unroll
            for (int n = 0; n < 32; ++n) t[n] = fmaf(xk, ws1[k * 32 + n], t[n]);
        }
        a_shoot = bs2[0];
#pragma unroll
        for (int k = 0; k < 32; ++k) a_shoot = fmaf(fmaxf(t[k], 0.0f), ws2[k], a_shoot);
    }

    //===================== value head: 53->64 relu ->32 relu ->1, h64 split in 32-halves =====================
    float value;
    {
        float h32[32];
#pragma unroll
        for (int n = 0; n < 32; ++n) h32[n] = bv2[n];

#pragma unroll 1
        for (int half = 0; half < 2; ++half) {
            float hh[32];
#pragma unroll
            for (int n = 0; n < 32; ++n) hh[n] = bv1[half * 32 + n];
#pragma unroll
            for (int k = 0; k < 53; ++k) {
                const float xk = base[k];
#pragma unroll
                for (int n = 0; n < 32; ++n) hh[n] = fmaf(xk, wv1[k * 64 + half * 32 + n], hh[n]);
            }
#pragma unroll
            for (int k = 0; k < 32; ++k) {
                const float xk = fmaxf(hh[k], 0.0f);
#pragma unroll
                for (int n = 0; n < 32; ++n) h32[n] = fmaf(xk, wv2[(half * 32 + k) * 32 + n], h32[n]);
            }
        }
        value = bv3[0];
#pragma unroll
        for (int k = 0; k < 32; ++k) value = fmaf(fmaxf(h32[k], 0.0f), wv3[k], value);
    }

    //===================== pass head shared part: pb = base @ wp1[32:85] + bp1  (base dies here) =====================
    float pb[64];
#pragma unroll
    for (int n = 0; n < 64; ++n) pb[n] = bp1[n];
#pragma unroll
    for (int k = 0; k < 53; ++k) {
        const float xk = base[k];
#pragma unroll
        for (int n = 0; n < 64; ++n) pb[n] = fmaf(xk, wp1[(32 + k) * 64 + n], pb[n]);
    }

    //===================== teammates: phi (18->32 relu ->32 relu), pass (85->64 relu ->16 relu ->1) =====================
    float ap0 = 0.f, ap1 = 0.f, ap2 = 0.f, ap3 = 0.f;
#pragma unroll 1
    for (int j = 0; j < 4; ++j) {
        float t1[32];
        {
            float tf[18];
            tf[0] = s[33 + 2 * j];   // tm_pos x
            tf[1] = s[34 + 2 * j];   // tm_pos y
            tf[2] = s[53 + 2 * j];   // tm_vel x
            tf[3] = s[54 + 2 * j];   // tm_vel y
            tf[4] = s[11 + j];       // tm_open
            tf[5] = s[15 + j];       // tm_fg
            tf[6] = s[19 + j];       // tm_dist
            tf[7] = s[61 + j];       // tm_lane_min
            tf[8] = s[65 + j];       // tm_corridor
            tf[9] = s[69 + j];       // tm_pass_dist
            {
                int pid = (int)s[74 + j];
                pid = pid < 0 ? 0 : (pid > 449 ? 449 : pid);
                const float4 e0 = *(const float4*)(emb + pid * 8);
                const float4 e1 = *(const float4*)(emb + pid * 8 + 4);
                tf[10] = e0.x; tf[11] = e0.y; tf[12] = e0.z; tf[13] = e0.w;
                tf[14] = e1.x; tf[15] = e1.y; tf[16] = e1.z; tf[17] = e1.w;
            }
#pragma unroll
            for (int n = 0; n < 32; ++n) t1[n] = bt1[n];
#pragma unroll
            for (int k = 0; k < 18; ++k) {
                const float xk = tf[k];
#pragma unroll
                for (int n = 0; n < 32; ++n) t1[n] = fmaf(xk, wt1[k * 32 + n], t1[n]);
            }
        }

        float t2[32];
#pragma unroll
        for (int n = 0; n < 32; ++n) t2[n] = bt2[n];
#pragma unroll
        for (int k = 0; k < 32; ++k) {
            const float xk = fmaxf(t1[k], 0.0f);
#pragma unroll
            for (int n = 0; n < 32; ++n) t2[n] = fmaf(xk, wt2[k * 32 + n], t2[n]);
        }
#pragma unroll
        for (int n = 0; n < 32; ++n) t2[n] = fmaxf(t2[n], 0.0f);  // tm_phi

        // pass MLP with ph split into 32-halves to cap liveness
        float p2[16];
#pragma unroll
        for (int n = 0; n < 16; ++n) p2[n] = bp2[n];

#pragma unroll 1
        for (int half = 0; half < 2; ++half) {
            float phh[32];
#pragma unroll
            for (int n = 0; n < 32; ++n) phh[n] = pb[half * 32 + n];
#pragma unroll
            for (int k = 0; k < 32; ++k) {
                const float xk = t2[k];
#pragma unroll
                for (int n = 0; n < 32; ++n) phh[n] = fmaf(xk, wp1[k * 64 + half * 32 + n], phh[n]);
            }
#pragma unroll
            for (int k = 0; k < 32; ++k) {
                const float xk = fmaxf(phh[k], 0.0f);
#pragma unroll
                for (int n = 0; n < 16; ++n) p2[n] = fmaf(xk, wp2[(half * 32 + k) * 16 + n], p2[n]);
            }
        }

        float a = bp3[0];
#pragma unroll
        for (int k = 0; k < 16; ++k) a = fmaf(fmaxf(p2[k], 0.0f), wp3[k], a);

        if (j == 0) ap0 = a;
        else if (j == 1) ap1 = a;
        else if (j == 2) ap2 = a;
        else ap3 = a;
    }

    //===================== combine & store =====================
    const float am = 0.25f * (ap0 + ap1 + ap2 + ap3);
    const float q0 = value + a_shoot;
    float* __restrict__ o = out + (long long)row * 5;
    o[0] = q0;
    o[1] = value + ap0 - am;
    o[2] = value + ap1 - am;
    o[3] = value + ap2 - am;
    o[4] = value + ap3 - am;
}

extern "C" void kernel_launch(void* const* d_in, const int* in_sizes, int n_in,
                              void* d_out, int out_size, void* d_ws, size_t ws_size,
                              hipStream_t stream)
{
    const float* state = (const float*)d_in[0];
    const float* emb   = (const float*)d_in[1];
    const float* wd1 = (const float*)d_in[2];  const float* bd1 = (const float*)d_in[3];
    const float* wd2 = (const float*)d_in[4];  const float* bd2 = (const float*)d_in[5];
    const float* wt1 = (const float*)d_in[6];  const float* bt1 = (const float*)d_in[7];
    const float* wt2 = (const float*)d_in[8];  const float* bt2 = (const float*)d_in[9];
    const float* wv1 = (const float*)d_in[10]; const float* bv1 = (const float*)d_in[11];
    const float* wv2 = (const float*)d_in[12]; const float* bv2 = (const float*)d_in[13];
    const float* wv3 = (const float*)d_in[14]; const float* bv3 = (const float*)d_in[15];
    const float* ws1 = (const float*)d_in[16]; const float* bs1 = (const float*)d_in[17];
    const float* ws2 = (const float*)d_in[18]; const float* bs2 = (const float*)d_in[19];
    const float* wp1 = (const float*)d_in[20]; const float* bp1 = (const float*)d_in[21];
    const float* wp2 = (const float*)d_in[22]; const float* bp2 = (const float*)d_in[23];
    const float* wp3 = (const float*)d_in[24]; const float* bp3 = (const float*)d_in[25];

    const int nrows = in_sizes[0] / 78;
    const int blocks = (nrows + THREADS - 1) / THREADS;
    dueling_fwd<<<blocks, THREADS, 0, stream>>>(
        state, emb,
        wd1, bd1, wd2, bd2, wt1, bt1, wt2, bt2,
        wv1, bv1, wv2, bv2, wv3, bv3, ws1, bs1, ws2, bs2,
        wp1, bp1, wp2, bp2, wp3, bp3,
        (float*)d_out, nrows);
}